// Round 9
// baseline (186.029 us; speedup 1.0000x reference)
//
#include <hip/hip_runtime.h>
#include <hip/hip_fp16.h>

// SAGEConv mean-aggr: out_i = mean_{j->i} x_j @ W_l^T + b_l + x_i @ W_r^T
//
// R1-R9: 481 -> 132.45 us. R10 fp16-hl: null. R11 fused 2:1 interleave:
//      127.7. R12 DMA proj: null. R13 3-way split: 153.7 (serialization).
// R14 CSR agg: +4. R16 2-atomic agg: -0.7. R17 scatter write-reorder: -1.2.
// DIAGNOSIS (R18): A runs 1.45 TB/s = 4x BELOW the ceiling the 42us fill
//      proves (6.3 TB/s) -> A was never byte-bound; bytes/ILP/DMA all null.
//      Ledger: fill 42 + A 41 + agg ~35-40 (never visible in top-5).
//      Agg's invariant-under-micro-fixes cost = the bucket machinery
//      itself (3.2M LDS u64 RMWs + phases + coarse 512-thr blocks).
// R18: DELETE the bucket structure. Per-node slotted sort:
//      scatter: slot=atomicAdd(&cursor[dst],1) (global, 100k cells,
//      ~16 collisions/addr total) -> sorted[dst*64+slot]=src. No LDS.
//      agg: 4 lanes/node read the node's contiguous <=64-entry segment,
//      gather hl, accumulate EXACT fp32 in registers, shfl-reduce, store.
//      Zero LDS, zero atomics, zero barriers, 1563x256 (~24 waves/CU).

#define N_NODES 100000
#define N_EDGES 1600000
#define D_IN 128

#define HR_STRIDE 8
#define N_PAD 100352                   // padded node count

#define CAP_NODE 64                    // slots per node; Poisson(16) max ~45
#define CAP_SHIFT 6

#define SC_EPT 16
#define SC_EPB (256 * SC_EPT)          // 4096 edges per scatter block
#define SC_GRID ((N_EDGES + SC_EPB - 1) / SC_EPB)   // 391

#define PROJ_NPB 128                   // nodes per proj block
#define PROJ_BLOCKS ((N_NODES + PROJ_NPB - 1) / PROJ_NPB)   // 782
// interleave 2 proj : 1 scatter; PROJ_BLOCKS == 2*SC_GRID == 782
#define FUSED_GRID (PROJ_BLOCKS + SC_GRID)                  // 1173

#define AGG_NPB 64                     // nodes per agg block (4 lanes/node)
#define AGG_BLOCKS ((N_NODES + AGG_NPB - 1) / AGG_NPB)      // 1563

typedef unsigned long long u64;
typedef unsigned int u32;

__device__ __forceinline__ float dot8(const float4 a0, const float4 a1,
                                      const float4 b0, const float4 b1) {
    return a0.x * b0.x + a0.y * b0.y + a0.z * b0.z + a0.w * b0.w
         + a1.x * b1.x + a1.y * b1.y + a1.z * b1.z + a1.w * b1.w;
}

// ---------------------------------------------------------------------------
// Fused kernel A: interleaved projection (2 of 3 blocks, exact R11 code) +
// per-node slotted scatter (1 of 3, LDS-free).
// ---------------------------------------------------------------------------
__global__ __launch_bounds__(256, 4) void proj_scatter_kernel(
    const float* __restrict__ x,
    const float* __restrict__ Wl,
    const float* __restrict__ Wr,
    uint4* __restrict__ hl,             // [N_PAD] 8xfp16 packed, first 5 valid
    float* __restrict__ hr,             // [N_PAD][8] f32, first 5 valid
    const int* __restrict__ ei,         // [2][N_EDGES]: row0 src, row1 dst
    u32* __restrict__ sorted,           // [N_PAD][CAP_NODE]
    int* __restrict__ cursor)           // [N_PAD], zero-initialized
{
    const int tid = threadIdx.x;
    const int m   = blockIdx.x % 3;
    const int d   = blockIdx.x / 3;

    if (m < 2) {
        // ---------------- projection (exact R11 code) ----------------
        const int pidx = d * 2 + m;      // 0..781
        const int g = tid >> 4;          // group 0..15
        const int k = tid & 15;          // lane within group, dims [8k,8k+8)
        const int node0 = pidx * PROJ_NPB + g * 8;

#pragma unroll
        for (int hb = 0; hb < 2; ++hb) {
            const int nb = node0 + hb * 4;

            float4 xv[4][2];
            int nodes[4];
#pragma unroll
            for (int it = 0; it < 4; ++it) {
                nodes[it] = min(nb + it, N_NODES - 1);
                const float4* xr =
                    (const float4*)(x + (size_t)nodes[it] * D_IN + k * 8);
                xv[it][0] = xr[0];
                xv[it][1] = xr[1];
            }

            // Wl pass
            {
                float4 wv[5][2];
#pragma unroll
                for (int o = 0; o < 5; ++o) {
                    const float* w = Wl + o * D_IN + k * 8;
                    wv[o][0] = ((const float4*)w)[0];
                    wv[o][1] = ((const float4*)w)[1];
                }
#pragma unroll
                for (int it = 0; it < 4; ++it) {
                    float s[5];
#pragma unroll
                    for (int o = 0; o < 5; ++o)
                        s[o] = dot8(xv[it][0], xv[it][1], wv[o][0], wv[o][1]);
#pragma unroll
                    for (int o = 0; o < 5; ++o) {
                        s[o] += __shfl_xor(s[o], 8, 64);
                        s[o] += __shfl_xor(s[o], 4, 64);
                        s[o] += __shfl_xor(s[o], 2, 64);
                        s[o] += __shfl_xor(s[o], 1, 64);
                    }
                    if (k == 0) {
                        u32 u0 = (u32)__half_as_ushort(__float2half_rn(s[0]));
                        u32 u1 = (u32)__half_as_ushort(__float2half_rn(s[1]));
                        u32 u2 = (u32)__half_as_ushort(__float2half_rn(s[2]));
                        u32 u3 = (u32)__half_as_ushort(__float2half_rn(s[3]));
                        u32 u4 = (u32)__half_as_ushort(__float2half_rn(s[4]));
                        uint4 pk;
                        pk.x = u0 | (u1 << 16);
                        pk.y = u2 | (u3 << 16);
                        pk.z = u4;
                        pk.w = 0u;
                        hl[nodes[it]] = pk;
                    }
                }
            }

            // Wr pass
            {
                float4 wv[5][2];
#pragma unroll
                for (int o = 0; o < 5; ++o) {
                    const float* w = Wr + o * D_IN + k * 8;
                    wv[o][0] = ((const float4*)w)[0];
                    wv[o][1] = ((const float4*)w)[1];
                }
#pragma unroll
                for (int it = 0; it < 4; ++it) {
                    float s[5];
#pragma unroll
                    for (int o = 0; o < 5; ++o)
                        s[o] = dot8(xv[it][0], xv[it][1], wv[o][0], wv[o][1]);
#pragma unroll
                    for (int o = 0; o < 5; ++o) {
                        s[o] += __shfl_xor(s[o], 8, 64);
                        s[o] += __shfl_xor(s[o], 4, 64);
                        s[o] += __shfl_xor(s[o], 2, 64);
                        s[o] += __shfl_xor(s[o], 1, 64);
                    }
                    if (k == 0) {
                        float* pr = hr + (size_t)nodes[it] * HR_STRIDE;
                        *(float4*)pr = make_float4(s[0], s[1], s[2], s[3]);
                        pr[4] = s[4];
                    }
                }
            }
        }
    } else {
        // -------- per-node slotted scatter (LDS-free) --------
        const int e0 = d * SC_EPB + tid * SC_EPT;

        int srcv[SC_EPT], dstv[SC_EPT];
        bool valid[SC_EPT];

        if (e0 + SC_EPT <= N_EDGES) {
            const int4* s4 = (const int4*)(ei + e0);
            const int4* d4 = (const int4*)(ei + N_EDGES + e0);
#pragma unroll
            for (int c = 0; c < SC_EPT / 4; ++c) {
                int4 sv = s4[c], dv = d4[c];
                srcv[c*4+0] = sv.x; srcv[c*4+1] = sv.y;
                srcv[c*4+2] = sv.z; srcv[c*4+3] = sv.w;
                dstv[c*4+0] = dv.x; dstv[c*4+1] = dv.y;
                dstv[c*4+2] = dv.z; dstv[c*4+3] = dv.w;
            }
#pragma unroll
            for (int q = 0; q < SC_EPT; ++q) valid[q] = true;
        } else {
#pragma unroll
            for (int q = 0; q < SC_EPT; ++q) {
                int e = e0 + q;
                valid[q] = (e < N_EDGES);
                srcv[q] = valid[q] ? ei[e] : 0;
                dstv[q] = valid[q] ? ei[N_EDGES + e] : 0;
            }
        }

#pragma unroll
        for (int q = 0; q < SC_EPT; ++q) {
            if (valid[q]) {
                int slot = atomicAdd(&cursor[dstv[q]], 1);
                if (slot < CAP_NODE)
                    sorted[((size_t)dstv[q] << CAP_SHIFT) + slot] =
                        (u32)srcv[q];
            }
        }
    }
}

// ---------------------------------------------------------------------------
// Kernel B: per-node register aggregation. 4 lanes per node; contiguous
// segment read + hl gather + exact fp32 accumulation; 2x shfl_xor reduce.
// No LDS, no atomics, no barriers.
// ---------------------------------------------------------------------------
__global__ __launch_bounds__(256) void agg_kernel(
    const u32* __restrict__ sorted,
    const int* __restrict__ cursor,
    const uint4* __restrict__ hl,
    const float* __restrict__ hr,
    const float* __restrict__ bias,
    float* __restrict__ out)
{
    const int tid  = threadIdx.x;
    const int sub  = tid & 3;           // lane within 4-lane node group
    const int nl   = tid >> 2;          // node within block, 0..63
    const int node = blockIdx.x * AGG_NPB + nl;
    if (node >= N_NODES) return;

    const u32 degf = (u32)cursor[node];
    const u32 deg  = min(degf, (u32)CAP_NODE);
    const u32* seg = sorted + ((size_t)node << CAP_SHIFT);

    float a0 = 0.f, a1 = 0.f, a2 = 0.f, a3 = 0.f, a4 = 0.f;
    for (u32 i = sub; i < deg; i += 4) {
        u32 s = seg[i];
        uint4 h = hl[s];
        a0 += __half2float(__ushort_as_half((unsigned short)(h.x & 0xFFFFu)));
        a1 += __half2float(__ushort_as_half((unsigned short)(h.x >> 16)));
        a2 += __half2float(__ushort_as_half((unsigned short)(h.y & 0xFFFFu)));
        a3 += __half2float(__ushort_as_half((unsigned short)(h.y >> 16)));
        a4 += __half2float(__ushort_as_half((unsigned short)(h.z & 0xFFFFu)));
    }

    // reduce across the 4-lane group (lanes nl*4 .. nl*4+3)
    a0 += __shfl_xor(a0, 1, 64); a0 += __shfl_xor(a0, 2, 64);
    a1 += __shfl_xor(a1, 1, 64); a1 += __shfl_xor(a1, 2, 64);
    a2 += __shfl_xor(a2, 1, 64); a2 += __shfl_xor(a2, 2, 64);
    a3 += __shfl_xor(a3, 1, 64); a3 += __shfl_xor(a3, 2, 64);
    a4 += __shfl_xor(a4, 1, 64); a4 += __shfl_xor(a4, 2, 64);

    if (sub == 0) {
        const float rec = 1.0f / fmaxf((float)deg, 1.0f);
        const float* h = hr + (size_t)node * HR_STRIDE;
        float* o = out + (size_t)node * 5;
        o[0] = a0 * rec + bias[0] + h[0];
        o[1] = a1 * rec + bias[1] + h[1];
        o[2] = a2 * rec + bias[2] + h[2];
        o[3] = a3 * rec + bias[3] + h[3];
        o[4] = a4 * rec + bias[4] + h[4];
    }
}

extern "C" void kernel_launch(void* const* d_in, const int* in_sizes, int n_in,
                              void* d_out, int out_size, void* d_ws, size_t ws_size,
                              hipStream_t stream) {
    const float* x    = (const float*)d_in[0];
    const int*   ei   = (const int*)d_in[1];
    const float* Wl   = (const float*)d_in[2];
    const float* bl   = (const float*)d_in[3];
    const float* Wr   = (const float*)d_in[4];
    float*       out  = (float*)d_out;

    // workspace layout (16B-aligned): ~31 MB total
    uint4* hl     = (uint4*)d_ws;                                 // N_PAD*16 B
    float* hr     = (float*)(hl + N_PAD);                         // N_PAD*8 f
    u32*   sorted = (u32*)(hr + (size_t)N_PAD * HR_STRIDE);       // N_PAD*64 u32
    int*   cursor = (int*)(sorted + ((size_t)N_PAD << CAP_SHIFT)); // N_PAD i32

    hipMemsetAsync(cursor, 0, N_PAD * sizeof(int), stream);

    proj_scatter_kernel<<<FUSED_GRID, 256, 0, stream>>>(
        x, Wl, Wr, hl, hr, ei, sorted, cursor);

    agg_kernel<<<AGG_BLOCKS, 256, 0, stream>>>(sorted, cursor, hl, hr, bl, out);
}

// Round 10
// 126.915 us; speedup vs baseline: 1.4658x; 1.4658x over previous
//
#include <hip/hip_runtime.h>
#include <hip/hip_fp16.h>

// SAGEConv mean-aggr: out_i = mean_{j->i} x_j @ W_l^T + b_l + x_i @ W_r^T
//
// R1-R9: 481 -> 132.45 us. R10 fp16-hl: null. R11 fused 2:1 interleave:
//      127.7. R12 DMA proj: null. R13 3-way split: 153.7 (serialization).
// R14 CSR agg: +4. R16 2-atomic agg: 126.98. R17 write-reorder: 125.81.
// R18 per-node slotted sort: 186 REGRESSION, but calibrated the model:
//      A is byte-proportional at a PINNED ~1.5 TB/s effective rate
//      (58.5MB->41.3us, 137MB->91.5us). Scattered 4B stores amplify 64x.
// R19: occupancy attack on the 1.5 TB/s: double the grid (2346 blocks =
//      9.2/CU), halve per-block work (PROJ_NPB 64, SC_EPT 8), keep the
//      4KB-LDS scatter (R17's 39KB reorder capped residency at 4 blk/CU
//      for ALL blocks -- LDS is per-workgroup regardless of branch).
//      Single variable vs R16. If A stays ~41us at higher occupancy, the
//      1.5 TB/s is a pattern limit -> roofline argument next round.

#define N_NODES 100000
#define N_EDGES 1600000
#define D_IN 128

#define HR_STRIDE 8
#define N_PAD 100352                   // padded node count

#define B_NODES 196                    // nodes per bucket
#define N_BUCKETS 512                  // 512*196 = 100352 >= N_NODES
#define CAP 3840                       // mean 3125, sigma ~56 -> +12.8 sigma

#define SC_EPT 8
#define SC_EPB (256 * SC_EPT)          // 2048 edges per scatter block
#define SC_GRID ((N_EDGES + SC_EPB - 1) / SC_EPB)   // 782

#define PROJ_NPB 64                    // nodes per proj block (1 pass of 4/group)
#define PROJ_BLOCKS (2 * SC_GRID)      // 1564 (covers 100096 >= N_NODES)
#define FUSED_GRID (PROJ_BLOCKS + SC_GRID)                  // 2346

// fixed-point: field = f*2^8 + 2^14 per addend, 21-bit field sums.
#define FX2S 256.0f
#define FX2B 16384u
#define FX2BF 16384.0f
#define INV_FX2S (1.0f / 256.0f)
#define FMASK 0x1FFFFFu

typedef unsigned long long u64;
typedef unsigned int u32;

__device__ __forceinline__ float dot8(const float4 a0, const float4 a1,
                                      const float4 b0, const float4 b1) {
    return a0.x * b0.x + a0.y * b0.y + a0.z * b0.z + a0.w * b0.w
         + a1.x * b1.x + a1.y * b1.y + a1.z * b1.z + a1.w * b1.w;
}

// ---------------------------------------------------------------------------
// Fused kernel A: interleaved projection (2 of 3 blocks) + counting-sort
// scatter (1 of 3). Half-size blocks vs R11 for 2x grid / higher occupancy.
// ---------------------------------------------------------------------------
__global__ __launch_bounds__(256, 4) void proj_scatter_kernel(
    const float* __restrict__ x,
    const float* __restrict__ Wl,
    const float* __restrict__ Wr,
    uint4* __restrict__ hl,             // [N_PAD] 8xfp16 packed, first 5 valid
    float* __restrict__ hr,             // [N_PAD][8] f32, first 5 valid
    const int* __restrict__ ei,         // [2][N_EDGES]: row0 src, row1 dst
    u32* __restrict__ sorted,           // [N_BUCKETS][CAP]
    int* __restrict__ cursor)           // [N_BUCKETS], zero-initialized
{
    const int tid = threadIdx.x;
    const int m   = blockIdx.x % 3;
    const int d   = blockIdx.x / 3;

    if (m < 2) {
        // ---------------- projection: 64 nodes, one 4-node pass ----------
        const int pidx = d * 2 + m;      // 0..1563
        const int g = tid >> 4;          // group 0..15
        const int k = tid & 15;          // lane within group, dims [8k,8k+8)
        const int nb = pidx * PROJ_NPB + g * 4;

        float4 xv[4][2];
        int nodes[4];
#pragma unroll
        for (int it = 0; it < 4; ++it) {
            // branch-free clamp: rows >= N_NODES recompute row N_NODES-1
            nodes[it] = min(nb + it, N_NODES - 1);
            const float4* xr =
                (const float4*)(x + (size_t)nodes[it] * D_IN + k * 8);
            xv[it][0] = xr[0];
            xv[it][1] = xr[1];
        }

        // Wl pass
        {
            float4 wv[5][2];
#pragma unroll
            for (int o = 0; o < 5; ++o) {
                const float* w = Wl + o * D_IN + k * 8;
                wv[o][0] = ((const float4*)w)[0];
                wv[o][1] = ((const float4*)w)[1];
            }
#pragma unroll
            for (int it = 0; it < 4; ++it) {
                float s[5];
#pragma unroll
                for (int o = 0; o < 5; ++o)
                    s[o] = dot8(xv[it][0], xv[it][1], wv[o][0], wv[o][1]);
#pragma unroll
                for (int o = 0; o < 5; ++o) {
                    s[o] += __shfl_xor(s[o], 8, 64);
                    s[o] += __shfl_xor(s[o], 4, 64);
                    s[o] += __shfl_xor(s[o], 2, 64);
                    s[o] += __shfl_xor(s[o], 1, 64);
                }
                if (k == 0) {
                    u32 u0 = (u32)__half_as_ushort(__float2half_rn(s[0]));
                    u32 u1 = (u32)__half_as_ushort(__float2half_rn(s[1]));
                    u32 u2 = (u32)__half_as_ushort(__float2half_rn(s[2]));
                    u32 u3 = (u32)__half_as_ushort(__float2half_rn(s[3]));
                    u32 u4 = (u32)__half_as_ushort(__float2half_rn(s[4]));
                    uint4 pk;
                    pk.x = u0 | (u1 << 16);
                    pk.y = u2 | (u3 << 16);
                    pk.z = u4;
                    pk.w = 0u;
                    hl[nodes[it]] = pk;
                }
            }
        }

        // Wr pass
        {
            float4 wv[5][2];
#pragma unroll
            for (int o = 0; o < 5; ++o) {
                const float* w = Wr + o * D_IN + k * 8;
                wv[o][0] = ((const float4*)w)[0];
                wv[o][1] = ((const float4*)w)[1];
            }
#pragma unroll
            for (int it = 0; it < 4; ++it) {
                float s[5];
#pragma unroll
                for (int o = 0; o < 5; ++o)
                    s[o] = dot8(xv[it][0], xv[it][1], wv[o][0], wv[o][1]);
#pragma unroll
                for (int o = 0; o < 5; ++o) {
                    s[o] += __shfl_xor(s[o], 8, 64);
                    s[o] += __shfl_xor(s[o], 4, 64);
                    s[o] += __shfl_xor(s[o], 2, 64);
                    s[o] += __shfl_xor(s[o], 1, 64);
                }
                if (k == 0) {
                    float* pr = hr + (size_t)nodes[it] * HR_STRIDE;
                    *(float4*)pr = make_float4(s[0], s[1], s[2], s[3]);
                    pr[4] = s[4];
                }
            }
        }
    } else {
        // ---------------- counting-sort scatter (4 KB LDS) ----------------
        __shared__ int hist[N_BUCKETS];
        __shared__ int basepos[N_BUCKETS];

        for (int i = tid; i < N_BUCKETS; i += 256) hist[i] = 0;
        __syncthreads();

        const int e0 = d * SC_EPB + tid * SC_EPT;

        int srcv[SC_EPT], dstv[SC_EPT], slot[SC_EPT];
        bool valid[SC_EPT];

        if (e0 + SC_EPT <= N_EDGES) {
            const int4* s4 = (const int4*)(ei + e0);
            const int4* d4 = (const int4*)(ei + N_EDGES + e0);
#pragma unroll
            for (int c = 0; c < SC_EPT / 4; ++c) {
                int4 sv = s4[c], dv = d4[c];
                srcv[c*4+0] = sv.x; srcv[c*4+1] = sv.y;
                srcv[c*4+2] = sv.z; srcv[c*4+3] = sv.w;
                dstv[c*4+0] = dv.x; dstv[c*4+1] = dv.y;
                dstv[c*4+2] = dv.z; dstv[c*4+3] = dv.w;
            }
#pragma unroll
            for (int q = 0; q < SC_EPT; ++q) valid[q] = true;
        } else {
#pragma unroll
            for (int q = 0; q < SC_EPT; ++q) {
                int e = e0 + q;
                valid[q] = (e < N_EDGES);
                srcv[q] = valid[q] ? ei[e] : 0;
                dstv[q] = valid[q] ? ei[N_EDGES + e] : 0;
            }
        }

#pragma unroll
        for (int q = 0; q < SC_EPT; ++q) {
            if (valid[q]) {
                unsigned b = (unsigned)dstv[q] / 196u;   // magic-mul div
                slot[q] = atomicAdd(&hist[b], 1);
            }
        }
        __syncthreads();

        for (int b = tid; b < N_BUCKETS; b += 256) {
            int c = hist[b];
            if (c > 0) basepos[b] = atomicAdd(&cursor[b], c);
        }
        __syncthreads();

#pragma unroll
        for (int q = 0; q < SC_EPT; ++q) {
            if (valid[q]) {
                unsigned b = (unsigned)dstv[q] / 196u;
                unsigned r = (unsigned)dstv[q] - b * 196u;
                sorted[(size_t)b * CAP + basepos[b] + slot[q]] =
                    (r << 17) | (unsigned)srcv[q];
            }
        }
    }
}

// ---------------------------------------------------------------------------
// Kernel B: per-bucket aggregation, TWO u64 LDS atomics per edge (R16).
// ---------------------------------------------------------------------------
__global__ __launch_bounds__(512) void agg_kernel(
    const u32* __restrict__ sorted,
    const int* __restrict__ cursor,
    const uint4* __restrict__ hl,
    const float* __restrict__ hr,
    const float* __restrict__ bias,
    float* __restrict__ out)
{
    __shared__ u64 accA[B_NODES];      // 1.6 KB
    __shared__ u64 accB[B_NODES];      // 1.6 KB

    const int b   = blockIdx.x;
    const int tid = threadIdx.x;

    for (int i = tid; i < B_NODES; i += 512) { accA[i] = 0ull; accB[i] = 0ull; }
    __syncthreads();

    const int cnt = cursor[b];
    const u32* sp = sorted + (size_t)b * CAP;
    const int nvec = cnt >> 2;

#define EMITH(hv, rr)                                                        \
    {                                                                        \
        float g0 = __half2float(__ushort_as_half((unsigned short)((hv).x & 0xFFFFu))); \
        float g1 = __half2float(__ushort_as_half((unsigned short)((hv).x >> 16)));     \
        float g2 = __half2float(__ushort_as_half((unsigned short)((hv).y & 0xFFFFu))); \
        float g3 = __half2float(__ushort_as_half((unsigned short)((hv).y >> 16)));     \
        float g4 = __half2float(__ushort_as_half((unsigned short)((hv).z & 0xFFFFu))); \
        u32 f0 = __float2uint_rn(fmaf(g0, FX2S, FX2BF));                     \
        u32 f1 = __float2uint_rn(fmaf(g1, FX2S, FX2BF));                     \
        u32 f2 = __float2uint_rn(fmaf(g2, FX2S, FX2BF));                     \
        u32 f3 = __float2uint_rn(fmaf(g3, FX2S, FX2BF));                     \
        u32 f4 = __float2uint_rn(fmaf(g4, FX2S, FX2BF));                     \
        atomicAdd(&accA[rr], (u64)f0 | ((u64)f1 << 21) | ((u64)f2 << 42));   \
        atomicAdd(&accB[rr], (u64)f3 | ((u64)f4 << 21) | (1ull << 42));      \
    }

    for (int it = tid; it < nvec; it += 512) {
        uint4 v = ((const uint4*)sp)[it];
        int s0 = (int)(v.x & 0x1FFFFu), r0 = (int)(v.x >> 17);
        int s1 = (int)(v.y & 0x1FFFFu), r1 = (int)(v.y >> 17);
        int s2 = (int)(v.z & 0x1FFFFu), r2 = (int)(v.z >> 17);
        int s3 = (int)(v.w & 0x1FFFFu), r3 = (int)(v.w >> 17);

        uint4 a0 = hl[s0];
        uint4 a1 = hl[s1];
        uint4 a2 = hl[s2];
        uint4 a3 = hl[s3];

        EMITH(a0, r0) EMITH(a1, r1) EMITH(a2, r2) EMITH(a3, r3)
    }
    for (int i = (nvec << 2) + tid; i < cnt; i += 512) {
        u32 v = sp[i];
        int src = (int)(v & 0x1FFFFu);
        int r   = (int)(v >> 17);
        uint4 a = hl[src];
        EMITH(a, r)
    }
#undef EMITH
    __syncthreads();

    const int nodebase = b * B_NODES;
    for (int n = tid; n < B_NODES; n += 512) {
        int node = nodebase + n;
        if (node >= N_NODES) continue;
        u64 wA = accA[n];
        u64 wB = accB[n];
        u32 deg = (u32)(wB >> 42);
        u32 db  = deg * FX2B;           // <= 85*16384 < 2^21, no wrap
        int i0 = (int)((u32)(wA        & FMASK) - db);
        int i1 = (int)((u32)((wA >> 21) & FMASK) - db);
        int i2 = (int)((u32)((wA >> 42) & FMASK) - db);
        int i3 = (int)((u32)(wB        & FMASK) - db);
        int i4 = (int)((u32)((wB >> 21) & FMASK) - db);

        float rec = INV_FX2S / fmaxf((float)deg, 1.0f);
        const float* h = hr + (size_t)node * HR_STRIDE;
        float* o = out + (size_t)node * 5;
        o[0] = (float)i0 * rec + bias[0] + h[0];
        o[1] = (float)i1 * rec + bias[1] + h[1];
        o[2] = (float)i2 * rec + bias[2] + h[2];
        o[3] = (float)i3 * rec + bias[3] + h[3];
        o[4] = (float)i4 * rec + bias[4] + h[4];
    }
}

extern "C" void kernel_launch(void* const* d_in, const int* in_sizes, int n_in,
                              void* d_out, int out_size, void* d_ws, size_t ws_size,
                              hipStream_t stream) {
    const float* x    = (const float*)d_in[0];
    const int*   ei   = (const int*)d_in[1];
    const float* Wl   = (const float*)d_in[2];
    const float* bl   = (const float*)d_in[3];
    const float* Wr   = (const float*)d_in[4];
    float*       out  = (float*)d_out;

    // workspace layout (16B-aligned): ~12.7 MB total
    uint4* hl     = (uint4*)d_ws;                                 // N_PAD*16 B
    float* hr     = (float*)(hl + N_PAD);                         // N_PAD*8 f
    u32*   sorted = (u32*)(hr + (size_t)N_PAD * HR_STRIDE);       // 512*3840 u32
    int*   cursor = (int*)(sorted + (size_t)N_BUCKETS * CAP);     // 512 i32

    hipMemsetAsync(cursor, 0, N_BUCKETS * sizeof(int), stream);

    proj_scatter_kernel<<<FUSED_GRID, 256, 0, stream>>>(
        x, Wl, Wr, hl, hr, ei, sorted, cursor);

    agg_kernel<<<N_BUCKETS, 512, 0, stream>>>(sorted, cursor, hl, hr, bl, out);
}